// Round 2
// baseline (260.176 us; speedup 1.0000x reference)
//
#include <hip/hip_runtime.h>

#define NS 7
#define NK 6
#define TW 294  // torsion row width = NS*NS*NK

// spherical Bessel j_n via upward recurrence (matches numpy/jnp closed form)
__device__ __forceinline__ float jl_runtime(float x, int n) {
    float s, c;
    sincosf(x, &s, &c);
    float inv = 1.0f / x;
    float j0 = s * inv;
    if (n == 0) return j0;
    float jm = j0;
    float j = (s * inv - c) * inv;
    for (int l = 2; l <= n; ++l) {
        float t = (float)(2 * l - 1) * inv * j - jm;
        jm = j;
        j = t;
    }
    return j;
}

// ws layout (floats): [0..41] z[l*6+i], [42..83] norm[l*6+i], [84..132] K[49 flat sph-harm]
__global__ void init_consts_kernel(float* __restrict__ ws) {
    __shared__ float zsh[NS][NK + NS - 1];
    const int total = NK + NS - 1;  // 12
    int tid = threadIdx.x;
    if (tid < total) zsh[0][tid] = (float)((tid + 1) * 3.14159265358979323846);
    __syncthreads();
    for (int l = 1; l < NS; ++l) {
        if (tid < total - l) {
            float a = zsh[l - 1][tid], b = zsh[l - 1][tid + 1];
            float fa = jl_runtime(a, l);
            for (int it = 0; it < 38; ++it) {
                float m = 0.5f * (a + b);
                float fm = jl_runtime(m, l);
                if (fa * fm <= 0.0f) { b = m; }
                else { a = m; fa = fm; }
            }
            zsh[l][tid] = 0.5f * (a + b);
        }
        __syncthreads();
    }
    if (tid < 42) {
        int l = tid / 6, i = tid % 6;
        float z = zsh[l][i];
        float jn1 = jl_runtime(z, l + 1);
        ws[tid] = z;
        ws[42 + tid] = 1.0f / sqrtf(0.5f * jn1 * jn1);
    }
    if (tid == 0) {
        double fact[13];
        fact[0] = 1.0;
        for (int i = 1; i < 13; ++i) fact[i] = fact[i - 1] * (double)i;
        const double PID = 3.14159265358979323846;
        ws[84] = (float)(0.5 / sqrt(PID));
        for (int l = 1; l < NS; ++l) {
            for (int m = -l; m <= l; ++m) {
                int am = m < 0 ? -m : m;
                double K = sqrt((2.0 * l + 1.0) / (4.0 * PID) * fact[l - am] / fact[l + am]);
                if (m != 0) K *= sqrt(2.0);
                ws[84 + l * l + m + l] = (float)K;
            }
        }
    }
}

__global__ void dist_emb_kernel(const float* __restrict__ dist,
                                const float* __restrict__ freq,
                                float* __restrict__ out, int E) {
    int e = blockIdx.x * blockDim.x + threadIdx.x;
    if (e >= E) return;
    float x = dist[e] * 0.2f;
    float inv = 1.0f / x;
    float x2 = x * x;
    float xp0 = x2 * x2 * x;  // x^5
    float env = inv - 28.0f * xp0 + 48.0f * xp0 * x - 21.0f * xp0 * x2;
    #pragma unroll
    for (int i = 0; i < NK; ++i) {
        out[(size_t)e * NK + i] = env * sinf(freq[i] * x);
    }
}

__launch_bounds__(64)
__global__ void triplet_kernel(const float* __restrict__ dist,
                               const float* __restrict__ angle,
                               const float* __restrict__ torsion,
                               const int* __restrict__ idx_kj,
                               const float* __restrict__ consts,
                               float* __restrict__ outA,
                               float* __restrict__ outT,
                               int T) {
    __shared__ float zc[42], nc[42], Kc[49];
    __shared__ float rbf_s[64][43];  // stride 43 (odd): <=2-way bank aliasing = free
    __shared__ float cbf_s[64][49];  // stride 49 (odd)
    const int lane = threadIdx.x;

    for (int j = lane; j < 133; j += 64) {
        float v = consts[j];
        if (j < 42) zc[j] = v;
        else if (j < 84) nc[j - 42] = v;
        else Kc[j - 84] = v;
    }

    const int t0 = blockIdx.x * 64;
    int t = t0 + lane;
    int tc = t < T ? t : T - 1;
    int idx = idx_kj[tc];
    float ang = angle[tc];
    float phi = torsion[tc];
    float x = dist[idx] * 0.2f;
    __syncthreads();  // consts ready

    // ---- rbf[42] for this lane's triplet, straight into LDS
    #pragma unroll
    for (int l = 0; l < NS; ++l) {
        #pragma unroll
        for (int i = 0; i < NK; ++i) {
            float arg = zc[l * 6 + i] * x;
            float s, c;
            sincosf(arg, &s, &c);
            float inv = 1.0f / arg;
            float j0 = s * inv;
            float val = j0;
            if (l >= 1) {
                float jm = j0;
                float jj = (s * inv - c) * inv;
                #pragma unroll
                for (int ll = 2; ll <= l; ++ll) {
                    float tmp = (float)(2 * ll - 1) * inv * jj - jm;
                    jm = jj;
                    jj = tmp;
                }
                val = jj;
            }
            rbf_s[lane][l * 6 + i] = nc[l * 6 + i] * val;
        }
    }

    // ---- associated Legendre (Condon-Shortley), fully unrolled -> registers
    float ct, st;
    sincosf(ang, &st, &ct);
    float P[NS][NS];
    P[0][0] = 1.0f;
    #pragma unroll
    for (int m = 1; m < NS; ++m) P[m][m] = (float)(1 - 2 * m) * P[m - 1][m - 1] * st;
    #pragma unroll
    for (int m = 0; m + 1 < NS; ++m) P[m + 1][m] = (float)(2 * m + 1) * ct * P[m][m];
    #pragma unroll
    for (int m = 0; m < NS; ++m) {
        #pragma unroll
        for (int l = m + 2; l < NS; ++l) {
            P[l][m] = ((float)(2 * l - 1) * ct * P[l - 1][m] -
                       (float)(l + m - 1) * P[l - 2][m]) / (float)(l - m);
        }
    }

    // sin/cos multiples of phi via Chebyshev recurrence
    float sp, cp;
    sincosf(phi, &sp, &cp);
    float sm[NS], cm[NS];
    sm[1] = sp; cm[1] = cp;
    #pragma unroll
    for (int m = 2; m < NS; ++m) {
        sm[m] = sm[m - 1] * cp + cm[m - 1] * sp;
        cm[m] = cm[m - 1] * cp - sm[m - 1] * sp;
    }

    // ---- cbf[49] flat: f = l*l + (m+l)
    cbf_s[lane][0] = Kc[0];
    #pragma unroll
    for (int l = 1; l < NS; ++l) {
        #pragma unroll
        for (int m = -l; m <= l; ++m) {
            int f = l * l + m + l;
            int am = m < 0 ? -m : m;
            float base;
            if (m < 0) base = sm[am] * P[l][am];
            else if (m == 0) base = P[l][0];
            else base = cm[am] * P[l][am];
            cbf_s[lane][f] = Kc[f] * base;
        }
    }
    __syncthreads();

    // ---- phase 2: coalesced stores. torsion col c = a*42 + r, r = l*6+i, c in [0,294)
    // value = cbf[a*7 + r/6] * rbf[r]
    int nvalid = T - t0; if (nvalid > 64) nvalid = 64;
    const int c0 = lane, c1 = lane + 64, c2 = lane + 128, c3 = lane + 192, c4 = lane + 256;
    const int a0 = c0 / 42, r0 = c0 - a0 * 42, q0 = a0 * 7 + r0 / 6;
    const int a1 = c1 / 42, r1 = c1 - a1 * 42, q1 = a1 * 7 + r1 / 6;
    const int a2 = c2 / 42, r2 = c2 - a2 * 42, q2 = a2 * 7 + r2 / 6;
    const int a3 = c3 / 42, r3 = c3 - a3 * 42, q3 = a3 * 7 + r3 / 6;
    const int a4 = c4 / 42, r4 = c4 - a4 * 42, q4 = a4 * 7 + r4 / 6;
    const int la = lane / 6;
    const int qa = la * la + la;  // cbf flat index of (l=la, m=0)
    float* bT = outT + (size_t)t0 * TW;
    float* bA = outA + (size_t)t0 * 42;
    for (int tt = 0; tt < nvalid; ++tt) {
        const float* rs = rbf_s[tt];
        const float* cs = cbf_s[tt];
        float* pT = bT + (size_t)tt * TW;
        pT[c0] = cs[q0] * rs[r0];
        pT[c1] = cs[q1] * rs[r1];
        pT[c2] = cs[q2] * rs[r2];
        pT[c3] = cs[q3] * rs[r3];
        if (lane < TW - 256) pT[c4] = cs[q4] * rs[r4];
        if (lane < 42) bA[(size_t)tt * 42 + lane] = cs[qa] * rs[lane];
    }
}

extern "C" void kernel_launch(void* const* d_in, const int* in_sizes, int n_in,
                              void* d_out, int out_size, void* d_ws, size_t ws_size,
                              hipStream_t stream) {
    const float* dist    = (const float*)d_in[0];
    const float* angle   = (const float*)d_in[1];
    const float* torsion = (const float*)d_in[2];
    const float* freq    = (const float*)d_in[3];
    const int*   idx_kj  = (const int*)d_in[4];
    const int E = in_sizes[0];
    const int T = in_sizes[1];
    float* out = (float*)d_out;
    float* consts = (float*)d_ws;

    init_consts_kernel<<<1, 64, 0, stream>>>(consts);
    dist_emb_kernel<<<(E + 255) / 256, 256, 0, stream>>>(dist, freq, out, E);
    float* outA = out + (size_t)E * NK;
    float* outT = outA + (size_t)T * 42;
    triplet_kernel<<<(T + 63) / 64, 64, 0, stream>>>(dist, angle, torsion, idx_kj,
                                                     consts, outA, outT, T);
}

// Round 3
// 233.012 us; speedup vs baseline: 1.1166x; 1.1166x over previous
//
#include <hip/hip_runtime.h>

#define NS 7
#define NK 6
#define TW 294  // torsion row width = NS*NS*NK

// spherical Bessel j_n via upward recurrence (matches numpy/jnp closed form)
__device__ __forceinline__ float jl_runtime(float x, int n) {
    float s, c;
    sincosf(x, &s, &c);
    float inv = 1.0f / x;
    float j0 = s * inv;
    if (n == 0) return j0;
    float jm = j0;
    float j = (s * inv - c) * inv;
    for (int l = 2; l <= n; ++l) {
        float t = (float)(2 * l - 1) * inv * j - jm;
        jm = j;
        j = t;
    }
    return j;
}

// ws layout (floats): [0..41] z[l*6+i], [42..83] norm[l*6+i], [84..132] K[49 flat sph-harm]
__global__ void init_consts_kernel(float* __restrict__ ws) {
    __shared__ float zsh[NS][NK + NS - 1];
    const int total = NK + NS - 1;  // 12
    int tid = threadIdx.x;
    if (tid < total) zsh[0][tid] = (float)((tid + 1) * 3.14159265358979323846);
    __syncthreads();
    for (int l = 1; l < NS; ++l) {
        if (tid < total - l) {
            float a = zsh[l - 1][tid], b = zsh[l - 1][tid + 1];
            float fa = jl_runtime(a, l);
            for (int it = 0; it < 38; ++it) {
                float m = 0.5f * (a + b);
                float fm = jl_runtime(m, l);
                if (fa * fm <= 0.0f) { b = m; }
                else { a = m; fa = fm; }
            }
            zsh[l][tid] = 0.5f * (a + b);
        }
        __syncthreads();
    }
    if (tid < 42) {
        int l = tid / 6, i = tid % 6;
        float z = zsh[l][i];
        float jn1 = jl_runtime(z, l + 1);
        ws[tid] = z;
        ws[42 + tid] = 1.0f / sqrtf(0.5f * jn1 * jn1);
    }
    if (tid == 0) {
        double fact[13];
        fact[0] = 1.0;
        for (int i = 1; i < 13; ++i) fact[i] = fact[i - 1] * (double)i;
        const double PID = 3.14159265358979323846;
        ws[84] = (float)(0.5 / sqrt(PID));
        for (int l = 1; l < NS; ++l) {
            for (int m = -l; m <= l; ++m) {
                int am = m < 0 ? -m : m;
                double K = sqrt((2.0 * l + 1.0) / (4.0 * PID) * fact[l - am] / fact[l + am]);
                if (m != 0) K *= sqrt(2.0);
                ws[84 + l * l + m + l] = (float)K;
            }
        }
    }
}

__global__ void dist_emb_kernel(const float* __restrict__ dist,
                                const float* __restrict__ freq,
                                float* __restrict__ out, int E) {
    int e = blockIdx.x * blockDim.x + threadIdx.x;
    if (e >= E) return;
    float x = dist[e] * 0.2f;
    float inv = 1.0f / x;
    float x2 = x * x;
    float xp0 = x2 * x2 * x;  // x^5
    float env = inv - 28.0f * xp0 + 48.0f * xp0 * x - 21.0f * xp0 * x2;
    #pragma unroll
    for (int i = 0; i < NK; ++i) {
        out[(size_t)e * NK + i] = env * sinf(freq[i] * x);
    }
}

__launch_bounds__(256)
__global__ void triplet_kernel(const float* __restrict__ dist,
                               const float* __restrict__ angle,
                               const float* __restrict__ torsion,
                               const int* __restrict__ idx_kj,
                               const float* __restrict__ consts,
                               float* __restrict__ outA,
                               float* __restrict__ outT,
                               int T) {
    __shared__ float zc[42], nc[42], Kc[49];
    __shared__ float rbf_s[64][43];  // stride 43 (odd): <=2-way bank aliasing = free
    __shared__ float cbf_s[64][49];  // stride 49 (odd)
    const int tid = threadIdx.x;

    for (int j = tid; j < 133; j += 256) {
        float v = consts[j];
        if (j < 42) zc[j] = v;
        else if (j < 84) nc[j - 42] = v;
        else Kc[j - 84] = v;
    }

    const int t0 = blockIdx.x * 64;
    __syncthreads();  // consts ready

    if (tid < 64) {
        // ---- cbf[49] for triplet slot `tid`
        int t = t0 + tid;
        int tc = t < T ? t : T - 1;
        float ang = angle[tc];
        float phi = torsion[tc];

        float ct, st;
        sincosf(ang, &st, &ct);
        float P[NS][NS];
        P[0][0] = 1.0f;
        #pragma unroll
        for (int m = 1; m < NS; ++m) P[m][m] = (float)(1 - 2 * m) * P[m - 1][m - 1] * st;
        #pragma unroll
        for (int m = 0; m + 1 < NS; ++m) P[m + 1][m] = (float)(2 * m + 1) * ct * P[m][m];
        #pragma unroll
        for (int m = 0; m < NS; ++m) {
            #pragma unroll
            for (int l = m + 2; l < NS; ++l) {
                P[l][m] = ((float)(2 * l - 1) * ct * P[l - 1][m] -
                           (float)(l + m - 1) * P[l - 2][m]) / (float)(l - m);
            }
        }

        float sp, cp;
        sincosf(phi, &sp, &cp);
        float sm[NS], cm[NS];
        sm[1] = sp; cm[1] = cp;
        #pragma unroll
        for (int m = 2; m < NS; ++m) {
            sm[m] = sm[m - 1] * cp + cm[m - 1] * sp;
            cm[m] = cm[m - 1] * cp - sm[m - 1] * sp;
        }

        cbf_s[tid][0] = Kc[0];
        #pragma unroll
        for (int l = 1; l < NS; ++l) {
            #pragma unroll
            for (int m = -l; m <= l; ++m) {
                int f = l * l + m + l;
                int am = m < 0 ? -m : m;
                float base;
                if (m < 0) base = sm[am] * P[l][am];
                else if (m == 0) base = P[l][0];
                else base = cm[am] * P[l][am];
                cbf_s[tid][f] = Kc[f] * base;
            }
        }
    } else {
        // ---- rbf: 3 threads per triplet, 14 Bessel evals each
        int w = tid - 64;              // 0..191
        int s = w / 3, p = w - 3 * s;  // slot, part
        int t = t0 + s;
        int tc = t < T ? t : T - 1;
        int idx = idx_kj[tc];
        float x = dist[idx] * 0.2f;
        int jlo = p * 14;
        for (int jj = jlo; jj < jlo + 14; ++jj) {
            int l = jj / 6;
            float arg = zc[jj] * x;
            float s1, c1;
            sincosf(arg, &s1, &c1);
            float inv = 1.0f / arg;
            float j0 = s1 * inv;
            float val = j0;
            if (l >= 1) {
                float jm = j0;
                float jcur = (s1 * inv - c1) * inv;
                for (int ll = 2; ll <= l; ++ll) {
                    float tmp = (float)(2 * ll - 1) * inv * jcur - jm;
                    jm = jcur;
                    jcur = tmp;
                }
                val = jcur;
            }
            rbf_s[s][jj] = nc[jj] * val;
        }
    }
    __syncthreads();

    // ---- phase 2: coalesced float2 stores, one wave per 16 triplets.
    // float2 slot s covers cols (2s, 2s+1): both share a = c/42 and q = a*7 + (c%42)/6
    // (42 and 6 even, c even => no boundary crossing inside a slot).
    const int wave = tid >> 6, lane = tid & 63;
    int nvalid = T - t0; if (nvalid > 64) nvalid = 64;
    const int s0 = lane, s1 = lane + 64, s2 = lane + 128;       // 147 slots total
    const int C0 = 2 * s0, A0 = C0 / 42, R0 = C0 - A0 * 42, Q0 = A0 * 7 + R0 / 6;
    const int C1 = 2 * s1, A1 = C1 / 42, R1 = C1 - A1 * 42, Q1 = A1 * 7 + R1 / 6;
    const int C2 = 2 * s2, A2 = C2 / 42, R2 = C2 - A2 * 42, Q2 = A2 * 7 + R2 / 6;
    const int la = (2 * lane) / 6;
    const int qa = la * la + la;  // cbf flat index of (l=la, m=0)

    float* bT = outT + (size_t)t0 * TW;
    float* bA = outA + (size_t)t0 * 42;
    int tlo = wave * 16;
    int thi = tlo + 16; if (thi > nvalid) thi = nvalid;
    for (int tt = tlo; tt < thi; ++tt) {
        const float* rs = rbf_s[tt];
        const float* cs = cbf_s[tt];
        float* pT = bT + (size_t)tt * TW;
        {
            float q = cs[Q0];
            *(float2*)(pT + C0) = make_float2(q * rs[R0], q * rs[R0 + 1]);
        }
        {
            float q = cs[Q1];
            *(float2*)(pT + C1) = make_float2(q * rs[R1], q * rs[R1 + 1]);
        }
        if (lane < 147 - 128) {
            float q = cs[Q2];
            *(float2*)(pT + C2) = make_float2(q * rs[R2], q * rs[R2 + 1]);
        }
        if (lane < 21) {
            float q = cs[qa];
            *(float2*)(bA + (size_t)tt * 42 + 2 * lane) =
                make_float2(q * rs[2 * lane], q * rs[2 * lane + 1]);
        }
    }
}

extern "C" void kernel_launch(void* const* d_in, const int* in_sizes, int n_in,
                              void* d_out, int out_size, void* d_ws, size_t ws_size,
                              hipStream_t stream) {
    const float* dist    = (const float*)d_in[0];
    const float* angle   = (const float*)d_in[1];
    const float* torsion = (const float*)d_in[2];
    const float* freq    = (const float*)d_in[3];
    const int*   idx_kj  = (const int*)d_in[4];
    const int E = in_sizes[0];
    const int T = in_sizes[1];
    float* out = (float*)d_out;
    float* consts = (float*)d_ws;

    init_consts_kernel<<<1, 64, 0, stream>>>(consts);
    dist_emb_kernel<<<(E + 255) / 256, 256, 0, stream>>>(dist, freq, out, E);
    float* outA = out + (size_t)E * NK;
    float* outT = outA + (size_t)T * 42;
    triplet_kernel<<<(T + 63) / 64, 256, 0, stream>>>(dist, angle, torsion, idx_kj,
                                                      consts, outA, outT, T);
}

// Round 4
// 222.413 us; speedup vs baseline: 1.1698x; 1.0477x over previous
//
#include <hip/hip_runtime.h>

#define NS 7
#define NK 6
#define TW 294   // torsion row width = NS*NS*NK
#define TPB 32   // triplets per block

// spherical Bessel j_n via upward recurrence (matches numpy/jnp closed form)
__device__ __forceinline__ float jl_runtime(float x, int n) {
    float s, c;
    sincosf(x, &s, &c);
    float inv = 1.0f / x;
    float j0 = s * inv;
    if (n == 0) return j0;
    float jm = j0;
    float j = (s * inv - c) * inv;
    for (int l = 2; l <= n; ++l) {
        float t = (float)(2 * l - 1) * inv * j - jm;
        jm = j;
        j = t;
    }
    return j;
}

// ws layout (floats): [0..41] z[l*6+i], [42..83] norm[l*6+i], [84..132] K[49 flat sph-harm]
__global__ void init_consts_kernel(float* __restrict__ ws) {
    __shared__ float zsh[NS][NK + NS - 1];
    const int total = NK + NS - 1;  // 12
    int tid = threadIdx.x;
    if (tid < total) zsh[0][tid] = (float)((tid + 1) * 3.14159265358979323846);
    __syncthreads();
    for (int l = 1; l < NS; ++l) {
        if (tid < total - l) {
            float a = zsh[l - 1][tid], b = zsh[l - 1][tid + 1];
            float fa = jl_runtime(a, l);
            for (int it = 0; it < 30; ++it) {
                float m = 0.5f * (a + b);
                float fm = jl_runtime(m, l);
                if (fa * fm <= 0.0f) { b = m; }
                else { a = m; fa = fm; }
            }
            zsh[l][tid] = 0.5f * (a + b);
        }
        __syncthreads();
    }
    if (tid < 42) {
        int l = tid / 6, i = tid % 6;
        float z = zsh[l][i];
        float jn1 = jl_runtime(z, l + 1);
        ws[tid] = z;
        ws[42 + tid] = 1.0f / sqrtf(0.5f * jn1 * jn1);
    }
    if (tid == 0) {
        double fact[13];
        fact[0] = 1.0;
        for (int i = 1; i < 13; ++i) fact[i] = fact[i - 1] * (double)i;
        const double PID = 3.14159265358979323846;
        ws[84] = (float)(0.5 / sqrt(PID));
        for (int l = 1; l < NS; ++l) {
            for (int m = -l; m <= l; ++m) {
                int am = m < 0 ? -m : m;
                double K = sqrt((2.0 * l + 1.0) / (4.0 * PID) * fact[l - am] / fact[l + am]);
                if (m != 0) K *= sqrt(2.0);
                ws[84 + l * l + m + l] = (float)K;
            }
        }
    }
}

__global__ void dist_emb_kernel(const float* __restrict__ dist,
                                const float* __restrict__ freq,
                                float* __restrict__ out, int E) {
    __shared__ __align__(16) float buf[256 * 6];
    const int tid = threadIdx.x;
    const int e0 = blockIdx.x * 256;
    int e = e0 + tid;
    int ec = e < E ? e : E - 1;
    float x = dist[ec] * 0.2f;
    float inv = 1.0f / x;
    float x2 = x * x;
    float xp0 = x2 * x2 * x;  // x^5
    float env = inv - 28.0f * xp0 + 48.0f * xp0 * x - 21.0f * xp0 * x2;
    float v[NK];
    #pragma unroll
    for (int i = 0; i < NK; ++i) v[i] = env * sinf(freq[i] * x);
    if (e0 + 256 <= E) {
        #pragma unroll
        for (int i = 0; i < NK; ++i) buf[tid * 6 + i] = v[i];
        __syncthreads();
        const float4* b4 = (const float4*)buf;
        float4* o4 = (float4*)(out + (size_t)e0 * 6);
        o4[tid] = b4[tid];
        if (tid < 128) o4[256 + tid] = b4[256 + tid];
    } else if (e < E) {
        #pragma unroll
        for (int i = 0; i < NK; ++i) out[(size_t)e * 6 + i] = v[i];
    }
}

__launch_bounds__(256, 8)
__global__ void triplet_kernel(const float* __restrict__ dist,
                               const float* __restrict__ angle,
                               const float* __restrict__ torsion,
                               const int* __restrict__ idx_kj,
                               const float* __restrict__ consts,
                               float* __restrict__ outA,
                               float* __restrict__ outT,
                               int T) {
    __shared__ float zc[42], nc[42], Kc[49];
    __shared__ __align__(16) float rbf_s[TPB][44];  // stride 44: even -> float2 reads stay 8B-aligned
    __shared__ float cbf_s[TPB][49];                 // stride 49 (odd): b32 only
    const int tid = threadIdx.x;

    if (tid < 133) {
        float v = consts[tid];
        if (tid < 42) zc[tid] = v;
        else if (tid < 84) nc[tid - 42] = v;
        else Kc[tid - 84] = v;
    }

    const int t0 = blockIdx.x * TPB;
    __syncthreads();  // consts ready

    if (tid < TPB) {
        // ---- cbf[49] for triplet slot `tid`, m-major to keep P liveness ~3 regs
        int t = t0 + tid;
        int tc = t < T ? t : T - 1;
        float ang = angle[tc];
        float phi = torsion[tc];

        float ct, st;
        sincosf(ang, &st, &ct);
        float sp, cp;
        sincosf(phi, &sp, &cp);
        float sm[NS], cm[NS];
        sm[1] = sp; cm[1] = cp;
        #pragma unroll
        for (int m = 2; m < NS; ++m) {
            sm[m] = sm[m - 1] * cp + cm[m - 1] * sp;
            cm[m] = cm[m - 1] * cp - sm[m - 1] * sp;
        }

        float* cb = cbf_s[tid];
        float pmm = 1.0f;  // P[m][m]
        #pragma unroll
        for (int m = 0; m < NS; ++m) {
            if (m > 0) pmm = (float)(1 - 2 * m) * pmm * st;
            // emit l = m
            {
                int f = m * m + m;
                if (m == 0) cb[f] = Kc[f];
                else {
                    cb[f + m] = Kc[f + m] * cm[m] * pmm;
                    cb[f - m] = Kc[f - m] * sm[m] * pmm;
                }
            }
            if (m < NS - 1) {
                float plm1 = pmm;
                float pl = (float)(2 * m + 1) * ct * pmm;  // P[m+1][m]
                {
                    int l = m + 1, f = l * l + l;
                    if (m == 0) cb[f] = Kc[f] * pl;
                    else {
                        cb[f + m] = Kc[f + m] * cm[m] * pl;
                        cb[f - m] = Kc[f - m] * sm[m] * pl;
                    }
                }
                #pragma unroll
                for (int l = m + 2; l < NS; ++l) {
                    float pn = ((float)(2 * l - 1) * ct * pl -
                                (float)(l + m - 1) * plm1) / (float)(l - m);
                    plm1 = pl; pl = pn;
                    int f = l * l + l;
                    if (m == 0) cb[f] = Kc[f] * pl;
                    else {
                        cb[f + m] = Kc[f + m] * cm[m] * pl;
                        cb[f - m] = Kc[f - m] * sm[m] * pl;
                    }
                }
            }
        }
    } else if (tid >= 64 && tid < 64 + 6 * TPB) {
        // ---- rbf: 6 threads per triplet, 7 Bessel evals each
        int w = tid - 64;
        int s = w / 6, p = w - 6 * s;
        int t = t0 + s;
        int tc = t < T ? t : T - 1;
        int idx = idx_kj[tc];
        float x = dist[idx] * 0.2f;
        int jlo = p * 7;
        for (int jj = jlo; jj < jlo + 7; ++jj) {
            int l = jj / 6;
            float arg = zc[jj] * x;
            float s1, c1;
            sincosf(arg, &s1, &c1);
            float inv = 1.0f / arg;
            float j0 = s1 * inv;
            float val = j0;
            if (l >= 1) {
                float jm = j0;
                float jcur = (s1 * inv - c1) * inv;
                for (int ll = 2; ll <= l; ++ll) {
                    float tmp = (float)(2 * ll - 1) * inv * jcur - jm;
                    jm = jcur;
                    jcur = tmp;
                }
                val = jcur;
            }
            rbf_s[s][jj] = nc[jj] * val;
        }
    }
    __syncthreads();

    // ---- phase 2: coalesced float2 stores; wave handles 8 triplets, unrolled.
    // float2 slot s covers cols (2s,2s+1): shares a = c/42 and q = a*7 + (c%42)/6.
    const int wave = tid >> 6, lane = tid & 63;
    const int C0 = 2 * lane,         A0 = C0 / 42, R0 = C0 - A0 * 42, Q0 = A0 * 7 + R0 / 6;
    const int C1 = 2 * (lane + 64),  A1 = C1 / 42, R1 = C1 - A1 * 42, Q1 = A1 * 7 + R1 / 6;
    const int C2 = 2 * (lane + 128), A2 = C2 / 42, R2 = C2 - A2 * 42, Q2 = A2 * 7 + R2 / 6;
    const int la = (2 * lane) / 6;
    const int qa = la * la + la;  // cbf flat index of (l=la, m=0)

    float* bT = outT + (size_t)t0 * TW;
    float* bA = outA + (size_t)t0 * 42;
    int nvalid = T - t0; if (nvalid > TPB) nvalid = TPB;
    const int tlo = wave * 8;

    if (nvalid == TPB) {
        #pragma unroll 2
        for (int k = 0; k < 8; ++k) {
            int tt = tlo + k;
            const float* rs = rbf_s[tt];
            const float2* rs2 = (const float2*)rs;
            const float* cs = cbf_s[tt];
            float* pT = bT + (size_t)tt * TW;
            {
                float q = cs[Q0]; float2 r = rs2[R0 >> 1];
                *(float2*)(pT + C0) = make_float2(q * r.x, q * r.y);
            }
            {
                float q = cs[Q1]; float2 r = rs2[R1 >> 1];
                *(float2*)(pT + C1) = make_float2(q * r.x, q * r.y);
            }
            if (lane < 19) {
                float q = cs[Q2]; float2 r = rs2[R2 >> 1];
                *(float2*)(pT + C2) = make_float2(q * r.x, q * r.y);
            }
            if (lane < 21) {
                float q = cs[qa]; float2 r = rs2[lane];
                *(float2*)(bA + (size_t)tt * 42 + 2 * lane) = make_float2(q * r.x, q * r.y);
            }
        }
    } else {
        int thi = tlo + 8; if (thi > nvalid) thi = nvalid;
        for (int tt = tlo; tt < thi; ++tt) {
            const float* rs = rbf_s[tt];
            const float2* rs2 = (const float2*)rs;
            const float* cs = cbf_s[tt];
            float* pT = bT + (size_t)tt * TW;
            {
                float q = cs[Q0]; float2 r = rs2[R0 >> 1];
                *(float2*)(pT + C0) = make_float2(q * r.x, q * r.y);
            }
            {
                float q = cs[Q1]; float2 r = rs2[R1 >> 1];
                *(float2*)(pT + C1) = make_float2(q * r.x, q * r.y);
            }
            if (lane < 19) {
                float q = cs[Q2]; float2 r = rs2[R2 >> 1];
                *(float2*)(pT + C2) = make_float2(q * r.x, q * r.y);
            }
            if (lane < 21) {
                float q = cs[qa]; float2 r = rs2[lane];
                *(float2*)(bA + (size_t)tt * 42 + 2 * lane) = make_float2(q * r.x, q * r.y);
            }
        }
    }
}

extern "C" void kernel_launch(void* const* d_in, const int* in_sizes, int n_in,
                              void* d_out, int out_size, void* d_ws, size_t ws_size,
                              hipStream_t stream) {
    const float* dist    = (const float*)d_in[0];
    const float* angle   = (const float*)d_in[1];
    const float* torsion = (const float*)d_in[2];
    const float* freq    = (const float*)d_in[3];
    const int*   idx_kj  = (const int*)d_in[4];
    const int E = in_sizes[0];
    const int T = in_sizes[1];
    float* out = (float*)d_out;
    float* consts = (float*)d_ws;

    init_consts_kernel<<<1, 64, 0, stream>>>(consts);
    dist_emb_kernel<<<(E + 255) / 256, 256, 0, stream>>>(dist, freq, out, E);
    float* outA = out + (size_t)E * NK;
    float* outT = outA + (size_t)T * 42;
    triplet_kernel<<<(T + TPB - 1) / TPB, 256, 0, stream>>>(dist, angle, torsion, idx_kj,
                                                            consts, outA, outT, T);
}

// Round 5
// 204.003 us; speedup vs baseline: 1.2754x; 1.0902x over previous
//
#include <hip/hip_runtime.h>

#define NS 7
#define NK 6
#define TW 294   // torsion row width = NS*NS*NK
#define TPB 32   // triplets per block

typedef float f4 __attribute__((ext_vector_type(4)));

// spherical Bessel j_n via upward recurrence (matches numpy/jnp closed form)
__device__ __forceinline__ float jl_runtime(float x, int n) {
    float s, c;
    sincosf(x, &s, &c);
    float inv = 1.0f / x;
    float j0 = s * inv;
    if (n == 0) return j0;
    float jm = j0;
    float j = (s * inv - c) * inv;
    for (int l = 2; l <= n; ++l) {
        float t = (float)(2 * l - 1) * inv * j - jm;
        jm = j;
        j = t;
    }
    return j;
}

// j_{l-1} and j_l together (for Newton)
__device__ __forceinline__ void jl_pair(float x, int l, float* jlm1, float* jl) {
    float s, c;
    sincosf(x, &s, &c);
    float inv = 1.0f / x;
    float jm = c * inv;        // j_{-1}
    float j = s * inv;         // j_0
    for (int ll = 1; ll <= l; ++ll) {
        float t = (float)(2 * ll - 1) * inv * j - jm;
        jm = j;
        j = t;
    }
    *jlm1 = jm;
    *jl = j;
}

// ws layout (floats): [0..41] z[l*6+i], [42..83] norm[l*6+i], [84..132] K[49 flat sph-harm]
__global__ void init_consts_kernel(float* __restrict__ ws) {
    __shared__ float zsh[NS][NK + NS - 1];
    const int total = NK + NS - 1;  // 12
    int tid = threadIdx.x;
    if (tid < total) zsh[0][tid] = (float)((tid + 1) * 3.14159265358979323846);
    __syncthreads();
    for (int l = 1; l < NS; ++l) {
        if (tid < total - l) {
            float a = zsh[l - 1][tid], b = zsh[l - 1][tid + 1];
            float fa = jl_runtime(a, l);
            for (int it = 0; it < 12; ++it) {   // bracket to ~1e-3
                float m = 0.5f * (a + b);
                float fm = jl_runtime(m, l);
                if (fa * fm <= 0.0f) { b = m; }
                else { a = m; fa = fm; }
            }
            float x = 0.5f * (a + b);
            #pragma unroll
            for (int it = 0; it < 3; ++it) {    // Newton polish
                float jm1, jv;
                jl_pair(x, l, &jm1, &jv);
                float d = jm1 - (float)(l + 1) / x * jv;  // j_l'(x)
                x -= jv / d;
            }
            zsh[l][tid] = x;
        }
        __syncthreads();
    }
    if (tid < 42) {
        int l = tid / 6, i = tid % 6;
        float z = zsh[l][i];
        float jn1 = jl_runtime(z, l + 1);
        ws[tid] = z;
        ws[42 + tid] = 1.0f / sqrtf(0.5f * jn1 * jn1);
    }
    if (tid < 49) {
        int f = tid;
        int l = 0;
        while ((l + 1) * (l + 1) <= f) ++l;
        int m = f - l * l - l;
        int am = m < 0 ? -m : m;
        float ratio = 1.0f;
        for (int t = l - am + 1; t <= l + am; ++t) ratio /= (float)t;
        float K = sqrtf((float)(2 * l + 1) * 0.07957747154594767f * ratio);
        if (m != 0) K *= 1.41421356237309505f;
        ws[84 + f] = K;
    }
}

__global__ void dist_emb_kernel(const float* __restrict__ dist,
                                const float* __restrict__ freq,
                                float* __restrict__ out, int E) {
    __shared__ __align__(16) float buf[256 * 6];
    const int tid = threadIdx.x;
    const int e0 = blockIdx.x * 256;
    int e = e0 + tid;
    int ec = e < E ? e : E - 1;
    float x = dist[ec] * 0.2f;
    float inv = 1.0f / x;
    float x2 = x * x;
    float xp0 = x2 * x2 * x;  // x^5
    float env = inv - 28.0f * xp0 + 48.0f * xp0 * x - 21.0f * xp0 * x2;
    float v[NK];
    #pragma unroll
    for (int i = 0; i < NK; ++i) v[i] = env * sinf(freq[i] * x);
    if (e0 + 256 <= E) {
        #pragma unroll
        for (int i = 0; i < NK; ++i) buf[tid * 6 + i] = v[i];
        __syncthreads();
        const f4* b4 = (const f4*)buf;
        f4* o4 = (f4*)(out + (size_t)e0 * 6);
        o4[tid] = b4[tid];
        if (tid < 128) o4[256 + tid] = b4[256 + tid];
    } else if (e < E) {
        #pragma unroll
        for (int i = 0; i < NK; ++i) out[(size_t)e * 6 + i] = v[i];
    }
}

__launch_bounds__(256, 4)
__global__ void triplet_kernel(const float* __restrict__ dist,
                               const float* __restrict__ angle,
                               const float* __restrict__ torsion,
                               const int* __restrict__ idx_kj,
                               const float* __restrict__ consts,
                               float* __restrict__ outA,
                               float* __restrict__ outT,
                               int T) {
    __shared__ __align__(16) float rbf_s[TPB][44];  // even stride: float2 reads 8B-aligned
    __shared__ float cbf_s[TPB][49];
    __shared__ __align__(16) float ob[16 * TW + 16 * 42];  // 5376 floats = 21504 B
    const int tid = threadIdx.x;
    const int t0 = blockIdx.x * TPB;
    const float* __restrict__ Kg = consts + 84;

    if (tid < TPB) {
        // ---- cbf[49] for triplet slot `tid`, m-major (3-deep P chain)
        int t = t0 + tid;
        int tc = t < T ? t : T - 1;
        float ang = angle[tc];
        float phi = torsion[tc];

        float ct, st;
        sincosf(ang, &st, &ct);
        float sp, cp;
        sincosf(phi, &sp, &cp);
        float sm[NS], cm[NS];
        sm[1] = sp; cm[1] = cp;
        #pragma unroll
        for (int m = 2; m < NS; ++m) {
            sm[m] = sm[m - 1] * cp + cm[m - 1] * sp;
            cm[m] = cm[m - 1] * cp - sm[m - 1] * sp;
        }

        float* cb = cbf_s[tid];
        float pmm = 1.0f;  // P[m][m]
        #pragma unroll
        for (int m = 0; m < NS; ++m) {
            if (m > 0) pmm = (float)(1 - 2 * m) * pmm * st;
            {
                int f = m * m + m;
                if (m == 0) cb[f] = Kg[f];
                else {
                    cb[f + m] = Kg[f + m] * cm[m] * pmm;
                    cb[f - m] = Kg[f - m] * sm[m] * pmm;
                }
            }
            if (m < NS - 1) {
                float plm1 = pmm;
                float pl = (float)(2 * m + 1) * ct * pmm;  // P[m+1][m]
                {
                    int l = m + 1, f = l * l + l;
                    if (m == 0) cb[f] = Kg[f] * pl;
                    else {
                        cb[f + m] = Kg[f + m] * cm[m] * pl;
                        cb[f - m] = Kg[f - m] * sm[m] * pl;
                    }
                }
                #pragma unroll
                for (int l = m + 2; l < NS; ++l) {
                    float pn = ((float)(2 * l - 1) * ct * pl -
                                (float)(l + m - 1) * plm1) / (float)(l - m);
                    plm1 = pl; pl = pn;
                    int f = l * l + l;
                    if (m == 0) cb[f] = Kg[f] * pl;
                    else {
                        cb[f + m] = Kg[f + m] * cm[m] * pl;
                        cb[f - m] = Kg[f - m] * sm[m] * pl;
                    }
                }
            }
        }
    } else if (tid >= 64 && tid < 64 + 6 * TPB) {
        // ---- rbf: 6 threads per triplet, 7 Bessel evals each
        int w = tid - 64;
        int s = w / 6, p = w - 6 * s;
        int t = t0 + s;
        int tc = t < T ? t : T - 1;
        int idx = idx_kj[tc];
        float x = dist[idx] * 0.2f;
        int jlo = p * 7;
        for (int jj = jlo; jj < jlo + 7; ++jj) {
            int l = jj / 6;
            float arg = consts[jj] * x;
            float s1, c1;
            sincosf(arg, &s1, &c1);
            float inv = 1.0f / arg;
            float j0 = s1 * inv;
            float val = j0;
            if (l >= 1) {
                float jm = j0;
                float jcur = (s1 * inv - c1) * inv;
                for (int ll = 2; ll <= l; ++ll) {
                    float tmp = (float)(2 * ll - 1) * inv * jcur - jm;
                    jm = jcur;
                    jcur = tmp;
                }
                val = jcur;
            }
            rbf_s[s][jj] = consts[42 + jj] * val;
        }
    }
    __syncthreads();

    // per-lane slot constants (float2 slot s -> cols 2s,2s+1 share a and q)
    const int wave = tid >> 6, lane = tid & 63;
    const int C0 = 2 * lane,         A0 = C0 / 42, R0 = C0 - A0 * 42, Q0 = A0 * 7 + R0 / 6;
    const int C1 = 2 * (lane + 64),  A1 = C1 / 42, R1 = C1 - A1 * 42, Q1 = A1 * 7 + R1 / 6;
    const int C2 = 2 * (lane + 128), A2 = C2 / 42, R2 = C2 - A2 * 42, Q2 = A2 * 7 + R2 / 6;
    const int la = (2 * lane) / 6;
    const int qa = la * la + la;  // cbf flat index of (l=la, m=0)

    int nvalid = T - t0; if (nvalid > TPB) nvalid = TPB;

    #pragma unroll
    for (int h = 0; h < 2; ++h) {
        // ---- 2a: products for rows [h*16, h*16+16) into contiguous LDS out-buffer
        #pragma unroll
        for (int k = 0; k < 4; ++k) {
            const int rl = wave * 4 + k;       // local row within half
            const int tt = h * 16 + rl;        // row within block
            const float2* rs2 = (const float2*)rbf_s[tt];
            const float* cs = cbf_s[tt];
            float* po = ob + rl * TW;
            {
                float q = cs[Q0]; float2 r = rs2[R0 >> 1];
                *(float2*)(po + C0) = make_float2(q * r.x, q * r.y);
            }
            {
                float q = cs[Q1]; float2 r = rs2[R1 >> 1];
                *(float2*)(po + C1) = make_float2(q * r.x, q * r.y);
            }
            if (lane < 19) {
                float q = cs[Q2]; float2 r = rs2[R2 >> 1];
                *(float2*)(po + C2) = make_float2(q * r.x, q * r.y);
            }
            if (lane < 21) {
                float q = cs[qa]; float2 r = rs2[lane];
                *(float2*)(ob + 16 * TW + rl * 42 + 2 * lane) = make_float2(q * r.x, q * r.y);
            }
        }
        __syncthreads();

        // ---- 2b: flat aligned dwordx4 copy LDS -> global (fill-kernel pattern)
        if (nvalid == TPB) {
            const f4* ob4 = (const f4*)ob;
            f4* gT = (f4*)(outT + (size_t)(t0 + h * 16) * TW);  // 16B-aligned (16*294*4 % 16 == 0)
            #pragma unroll
            for (int it = 0; it < 5; ++it) {
                int g = it * 256 + tid;
                if (g < (16 * TW) / 4) __builtin_nontemporal_store(ob4[g], gT + g);
            }
            f4* gA = (f4*)(outA + (size_t)(t0 + h * 16) * 42);
            if (tid < (16 * 42) / 4) __builtin_nontemporal_store(ob4[(16 * TW) / 4 + tid], gA + tid);
        } else {
            int nh = nvalid - h * 16;
            if (nh < 0) nh = 0;
            if (nh > 16) nh = 16;
            for (int g = tid; g < nh * TW; g += 256)
                outT[(size_t)(t0 + h * 16) * TW + g] = ob[g];
            for (int g = tid; g < nh * 42; g += 256)
                outA[(size_t)(t0 + h * 16) * 42 + g] = ob[16 * TW + g];
        }
        __syncthreads();
    }
}

extern "C" void kernel_launch(void* const* d_in, const int* in_sizes, int n_in,
                              void* d_out, int out_size, void* d_ws, size_t ws_size,
                              hipStream_t stream) {
    const float* dist    = (const float*)d_in[0];
    const float* angle   = (const float*)d_in[1];
    const float* torsion = (const float*)d_in[2];
    const float* freq    = (const float*)d_in[3];
    const int*   idx_kj  = (const int*)d_in[4];
    const int E = in_sizes[0];
    const int T = in_sizes[1];
    float* out = (float*)d_out;
    float* consts = (float*)d_ws;

    init_consts_kernel<<<1, 64, 0, stream>>>(consts);
    dist_emb_kernel<<<(E + 255) / 256, 256, 0, stream>>>(dist, freq, out, E);
    float* outA = out + (size_t)E * NK;
    float* outT = outA + (size_t)T * 42;
    triplet_kernel<<<(T + TPB - 1) / TPB, 256, 0, stream>>>(dist, angle, torsion, idx_kj,
                                                            consts, outA, outT, T);
}

// Round 6
// 188.728 us; speedup vs baseline: 1.3786x; 1.0809x over previous
//
#include <hip/hip_runtime.h>

#define NS 7
#define NK 6
#define TW 294   // torsion row width = NS*NS*NK
#define TPB 32   // triplets per block

typedef float f4 __attribute__((ext_vector_type(4)));

// spherical Bessel j_n via upward recurrence (matches numpy/jnp closed form)
__device__ __forceinline__ float jl_runtime(float x, int n) {
    float s, c;
    sincosf(x, &s, &c);
    float inv = 1.0f / x;
    float j0 = s * inv;
    if (n == 0) return j0;
    float jm = j0;
    float j = (s * inv - c) * inv;
    for (int l = 2; l <= n; ++l) {
        float t = (float)(2 * l - 1) * inv * j - jm;
        jm = j;
        j = t;
    }
    return j;
}

// j_{l-1} and j_l together (for Newton)
__device__ __forceinline__ void jl_pair(float x, int l, float* jlm1, float* jl) {
    float s, c;
    sincosf(x, &s, &c);
    float inv = 1.0f / x;
    float jm = c * inv;        // j_{-1}
    float j = s * inv;         // j_0
    for (int ll = 1; ll <= l; ++ll) {
        float t = (float)(2 * ll - 1) * inv * j - jm;
        jm = j;
        j = t;
    }
    *jlm1 = jm;
    *jl = j;
}

// ws layout (floats): [0..41] z[l*6+i], [42..83] norm[l*6+i], [84..132] K[49 flat sph-harm]
__global__ void init_consts_kernel(float* __restrict__ ws) {
    __shared__ float zsh[NS][NK + NS - 1];
    const int total = NK + NS - 1;  // 12
    int tid = threadIdx.x;
    if (tid < total) zsh[0][tid] = (float)((tid + 1) * 3.14159265358979323846);
    __syncthreads();
    for (int l = 1; l < NS; ++l) {
        if (tid < total - l) {
            float a = zsh[l - 1][tid], b = zsh[l - 1][tid + 1];
            float fa = jl_runtime(a, l);
            for (int it = 0; it < 12; ++it) {   // bracket to ~1e-3
                float m = 0.5f * (a + b);
                float fm = jl_runtime(m, l);
                if (fa * fm <= 0.0f) { b = m; }
                else { a = m; fa = fm; }
            }
            float x = 0.5f * (a + b);
            #pragma unroll
            for (int it = 0; it < 3; ++it) {    // Newton polish
                float jm1, jv;
                jl_pair(x, l, &jm1, &jv);
                float d = jm1 - (float)(l + 1) / x * jv;  // j_l'(x)
                x -= jv / d;
            }
            zsh[l][tid] = x;
        }
        __syncthreads();
    }
    if (tid < 42) {
        int l = tid / 6, i = tid % 6;
        float z = zsh[l][i];
        float jn1 = jl_runtime(z, l + 1);
        ws[tid] = z;
        ws[42 + tid] = 1.0f / sqrtf(0.5f * jn1 * jn1);
    }
    if (tid < 49) {
        int f = tid;
        int l = 0;
        while ((l + 1) * (l + 1) <= f) ++l;
        int m = f - l * l - l;
        int am = m < 0 ? -m : m;
        float ratio = 1.0f;
        for (int t = l - am + 1; t <= l + am; ++t) ratio /= (float)t;
        float K = sqrtf((float)(2 * l + 1) * 0.07957747154594767f * ratio);
        if (m != 0) K *= 1.41421356237309505f;
        ws[84 + f] = K;
    }
}

__global__ void dist_emb_kernel(const float* __restrict__ dist,
                                const float* __restrict__ freq,
                                float* __restrict__ out, int E) {
    __shared__ __align__(16) float buf[256 * 6];
    const int tid = threadIdx.x;
    const int e0 = blockIdx.x * 256;
    int e = e0 + tid;
    int ec = e < E ? e : E - 1;
    float x = dist[ec] * 0.2f;
    float inv = 1.0f / x;
    float x2 = x * x;
    float xp0 = x2 * x2 * x;  // x^5
    float env = inv - 28.0f * xp0 + 48.0f * xp0 * x - 21.0f * xp0 * x2;
    float v[NK];
    #pragma unroll
    for (int i = 0; i < NK; ++i) v[i] = env * sinf(freq[i] * x);
    if (e0 + 256 <= E) {
        #pragma unroll
        for (int i = 0; i < NK; ++i) buf[tid * 6 + i] = v[i];
        __syncthreads();
        const f4* b4 = (const f4*)buf;
        f4* o4 = (f4*)(out + (size_t)e0 * 6);
        o4[tid] = b4[tid];
        if (tid < 128) o4[256 + tid] = b4[256 + tid];
    } else if (e < E) {
        #pragma unroll
        for (int i = 0; i < NK; ++i) out[(size_t)e * 6 + i] = v[i];
    }
}

__launch_bounds__(256, 8)
__global__ void triplet_kernel(const float* __restrict__ dist,
                               const float* __restrict__ angle,
                               const float* __restrict__ torsion,
                               const int* __restrict__ idx_kj,
                               const float* __restrict__ consts,
                               float* __restrict__ outA,
                               float* __restrict__ outT,
                               int T) {
    __shared__ __align__(16) float rbf_s[TPB][44];  // even stride: b64 reads stay 8B-aligned
    __shared__ float cbf_s[TPB][49];                // odd stride: good bank spread
    const int tid = threadIdx.x;
    const int t0 = blockIdx.x * TPB;
    const float* __restrict__ Kg = consts + 84;

    if (tid < TPB) {
        // ---- cbf[49] for triplet slot `tid`, m-major (3-deep P chain)
        int t = t0 + tid;
        int tc = t < T ? t : T - 1;
        float ang = angle[tc];
        float phi = torsion[tc];

        float ct, st;
        sincosf(ang, &st, &ct);
        float sp, cp;
        sincosf(phi, &sp, &cp);
        float sm[NS], cm[NS];
        sm[1] = sp; cm[1] = cp;
        #pragma unroll
        for (int m = 2; m < NS; ++m) {
            sm[m] = sm[m - 1] * cp + cm[m - 1] * sp;
            cm[m] = cm[m - 1] * cp - sm[m - 1] * sp;
        }

        float* cb = cbf_s[tid];
        float pmm = 1.0f;  // P[m][m]
        #pragma unroll
        for (int m = 0; m < NS; ++m) {
            if (m > 0) pmm = (float)(1 - 2 * m) * pmm * st;
            {
                int f = m * m + m;
                if (m == 0) cb[f] = Kg[f];
                else {
                    cb[f + m] = Kg[f + m] * cm[m] * pmm;
                    cb[f - m] = Kg[f - m] * sm[m] * pmm;
                }
            }
            if (m < NS - 1) {
                float plm1 = pmm;
                float pl = (float)(2 * m + 1) * ct * pmm;  // P[m+1][m]
                {
                    int l = m + 1, f = l * l + l;
                    if (m == 0) cb[f] = Kg[f] * pl;
                    else {
                        cb[f + m] = Kg[f + m] * cm[m] * pl;
                        cb[f - m] = Kg[f - m] * sm[m] * pl;
                    }
                }
                #pragma unroll
                for (int l = m + 2; l < NS; ++l) {
                    float pn = ((float)(2 * l - 1) * ct * pl -
                                (float)(l + m - 1) * plm1) / (float)(l - m);
                    plm1 = pl; pl = pn;
                    int f = l * l + l;
                    if (m == 0) cb[f] = Kg[f] * pl;
                    else {
                        cb[f + m] = Kg[f + m] * cm[m] * pl;
                        cb[f - m] = Kg[f - m] * sm[m] * pl;
                    }
                }
            }
        }
    } else if (tid >= 64 && tid < 64 + 6 * TPB) {
        // ---- rbf: 6 threads per triplet, 7 Bessel evals each
        int w = tid - 64;
        int s = w / 6, p = w - 6 * s;
        int t = t0 + s;
        int tc = t < T ? t : T - 1;
        int idx = idx_kj[tc];
        float x = dist[idx] * 0.2f;
        int jlo = p * 7;
        for (int jj = jlo; jj < jlo + 7; ++jj) {
            int l = jj / 6;
            float arg = consts[jj] * x;
            float s1, c1;
            sincosf(arg, &s1, &c1);
            float inv = 1.0f / arg;
            float j0 = s1 * inv;
            float val = j0;
            if (l >= 1) {
                float jm = j0;
                float jcur = (s1 * inv - c1) * inv;
                for (int ll = 2; ll <= l; ++ll) {
                    float tmp = (float)(2 * ll - 1) * inv * jcur - jm;
                    jm = jcur;
                    jcur = tmp;
                }
                val = jcur;
            }
            rbf_s[s][jj] = consts[42 + jj] * val;
        }
    }
    __syncthreads();

    int nvalid = T - t0; if (nvalid > TPB) nvalid = TPB;

    if (nvalid == TPB) {
        // ---- phase 2: direct register products -> flat nontemporal dwordx4 stores.
        // Torsion block region = 32*294 floats = 2352 x 16B chunks.
        // Chunk at flat 4g: cols (c,c+1) of `row` and (c+2,c+3) (may wrap to row+1).
        // Even col-pair shares a = c/42 and q = a*7 + (c%42)/6 (q never splits a pair).
        f4* __restrict__ gT = (f4*)(outT + (size_t)t0 * TW);
        unsigned row = (unsigned)(4 * tid) / 294u;
        unsigned c   = (unsigned)(4 * tid) - row * 294u;
        #pragma unroll
        for (int it = 0; it < 10; ++it) {
            if (it < 9 || tid < 48) {
                unsigned row1 = row, c1 = c + 2;
                if (c1 >= 294u) { c1 -= 294u; row1 += 1; }
                unsigned a0 = c / 42u,  r0 = c - a0 * 42u,  q0 = a0 * 7u + r0 / 6u;
                unsigned a1 = c1 / 42u, r1 = c1 - a1 * 42u, q1 = a1 * 7u + r1 / 6u;
                float qv0 = cbf_s[row][q0];
                float2 rv0 = *(const float2*)&rbf_s[row][r0];
                float qv1 = cbf_s[row1][q1];
                float2 rv1 = *(const float2*)&rbf_s[row1][r1];
                f4 val = { qv0 * rv0.x, qv0 * rv0.y, qv1 * rv1.x, qv1 * rv1.y };
                __builtin_nontemporal_store(val, gT + it * 256 + tid);
            }
            c += 142u; row += 3u;
            if (c >= 294u) { c -= 294u; row += 1u; }
        }
        // Angle block region = 32*42 floats = 336 x 16B chunks.
        f4* __restrict__ gA = (f4*)(outA + (size_t)t0 * 42);
        unsigned arow = (unsigned)(4 * tid) / 42u;
        unsigned ac   = (unsigned)(4 * tid) - arow * 42u;
        #pragma unroll
        for (int it = 0; it < 2; ++it) {
            if (it < 1 || tid < 80) {
                unsigned arow1 = arow, ac1 = ac + 2;
                if (ac1 >= 42u) { ac1 -= 42u; arow1 += 1; }
                unsigned l0 = ac / 6u,  qa0 = l0 * l0 + l0;
                unsigned l1 = ac1 / 6u, qa1 = l1 * l1 + l1;
                float qv0 = cbf_s[arow][qa0];
                float2 rv0 = *(const float2*)&rbf_s[arow][ac];
                float qv1 = cbf_s[arow1][qa1];
                float2 rv1 = *(const float2*)&rbf_s[arow1][ac1];
                f4 val = { qv0 * rv0.x, qv0 * rv0.y, qv1 * rv1.x, qv1 * rv1.y };
                __builtin_nontemporal_store(val, gA + it * 256 + tid);
            }
            ac += 16u; arow += 24u;  // +1024 floats = 24*42 + 16
            if (ac >= 42u) { ac -= 42u; arow += 1u; }
        }
    } else {
        // partial tail block (not hit when T % TPB == 0) — safe scalar path
        for (int g = tid; g < nvalid * TW; g += 256) {
            int row = g / TW, cc = g - row * TW;
            int a = cc / 42, r = cc - a * 42;
            outT[(size_t)t0 * TW + g] = cbf_s[row][a * 7 + r / 6] * rbf_s[row][r];
        }
        for (int g = tid; g < nvalid * 42; g += 256) {
            int row = g / 42, r = g - row * 42;
            int l = r / 6;
            outA[(size_t)t0 * 42 + g] = cbf_s[row][l * l + l] * rbf_s[row][r];
        }
    }
}

extern "C" void kernel_launch(void* const* d_in, const int* in_sizes, int n_in,
                              void* d_out, int out_size, void* d_ws, size_t ws_size,
                              hipStream_t stream) {
    const float* dist    = (const float*)d_in[0];
    const float* angle   = (const float*)d_in[1];
    const float* torsion = (const float*)d_in[2];
    const float* freq    = (const float*)d_in[3];
    const int*   idx_kj  = (const int*)d_in[4];
    const int E = in_sizes[0];
    const int T = in_sizes[1];
    float* out = (float*)d_out;
    float* consts = (float*)d_ws;

    init_consts_kernel<<<1, 64, 0, stream>>>(consts);
    dist_emb_kernel<<<(E + 255) / 256, 256, 0, stream>>>(dist, freq, out, E);
    float* outA = out + (size_t)E * NK;
    float* outT = outA + (size_t)T * 42;
    triplet_kernel<<<(T + TPB - 1) / TPB, 256, 0, stream>>>(dist, angle, torsion, idx_kj,
                                                            consts, outA, outT, T);
}